// Round 16
// baseline (682.795 us; speedup 1.0000x reference)
//
#include <hip/hip_runtime.h>
#include <hip/hip_fp16.h>
#include <stdint.h>

// Problem constants (GatedGraphConv_26585847562966)
#define NN  100000   // nodes
#define DD  128      // feature dim
#define TT  3        // timesteps
#define ETT 4        // edge types
#define EE  250000   // edges per type
#define NCH 49       // scan chunks per etype (2048 elems each)

typedef float  f32x4  __attribute__((ext_vector_type(4)));
typedef __bf16 bf16x8 __attribute__((ext_vector_type(8)));

__device__ __forceinline__ float bf2f(uint32_t u){ u <<= 16; return __builtin_bit_cast(float, u); }
__device__ __forceinline__ uint32_t f2bf(float f){
  uint32_t u = __builtin_bit_cast(uint32_t, f);
  return (u + 0x7FFFu + ((u >> 16) & 1u)) >> 16;   // RNE, low 16 bits valid
}
__device__ __forceinline__ float h2f(uint32_t u){ return __half2float(__ushort_as_half((uint16_t)u)); }
__device__ __forceinline__ uint32_t f2h(float f){ return (uint32_t)__half_as_ushort(__float2half(f)); }
__device__ __forceinline__ f32x4 mfma16(bf16x8 a, bf16x8 b, f32x4 c){
  return __builtin_amdgcn_mfma_f32_16x16x32_bf16(a, b, c, 0, 0, 0);
}
// acc = fp16(lo/hi half of h) * v + acc, single VOP3P instruction
__device__ __forceinline__ void fmamix_lo(float& acc, uint32_t h, float v){
  asm("v_fma_mix_f32 %0, %1, %2, %0 op_sel:[0,0,0] op_sel_hi:[1,0,0]"
      : "+v"(acc) : "v"(h), "v"(v));
}
__device__ __forceinline__ void fmamix_hi(float& acc, uint32_t h, float v){
  asm("v_fma_mix_f32 %0, %1, %2, %0 op_sel:[1,0,0] op_sel_hi:[1,0,0]"
      : "+v"(acc) : "v"(h), "v"(v));
}

// ---------------------------------------------------------------- CSR build (per etype)
__global__ void k_count(const int* __restrict__ erow, int* __restrict__ counts){
  int idx = blockIdx.x * 256 + threadIdx.x;
  if (idx >= ETT * EE) return;
  int e = idx / EE;
  atomicAdd(&counts[e * NN + erow[idx]], 1);
}

__global__ void k_blksum(const int* __restrict__ counts, int* __restrict__ bsum){
  const int b = blockIdx.x, e = b / NCH, c = b % NCH;
  const int* p = counts + e * NN + c * 2048;
  int lim = NN - c * 2048; if (lim > 2048) lim = 2048;
  const int t = threadIdx.x;
  int s = 0;
  #pragma unroll
  for (int i = 0; i < 8; ++i){
    int idx = i * 256 + t;
    if (idx < lim) s += p[idx];
  }
  #pragma unroll
  for (int d = 32; d; d >>= 1) s += __shfl_down(s, d);
  __shared__ int wsum[4];
  if ((t & 63) == 0) wsum[t >> 6] = s;
  __syncthreads();
  if (t == 0) bsum[b] = wsum[0] + wsum[1] + wsum[2] + wsum[3];
}

// per-chunk exclusive scan; block-local re-reduction of bsum gives the chunk base
__global__ void k_apply(const int* __restrict__ counts, const int* __restrict__ bsum,
                        int* __restrict__ offsets){
  const int b = blockIdx.x, e = b / NCH, c = b % NCH;
  const int* p = counts + e * NN + c * 2048;
  int* off = offsets + e * (NN + 1) + c * 2048;
  int lim = NN - c * 2048; if (lim > 2048) lim = 2048;
  const int t = threadIdx.x, l = t & 63, wid = t >> 6;
  __shared__ int wt[4];
  __shared__ int s_bexc;
  if (wid == 0){                                  // chunk base = sum of prior chunk sums
    int vb = (l < c) ? bsum[e * NCH + l] : 0;
    #pragma unroll
    for (int d = 32; d; d >>= 1) vb += __shfl_down(vb, d);
    if (l == 0) s_bexc = vb;
  }
  int v[8], s = 0;
  #pragma unroll
  for (int i = 0; i < 8; ++i){
    int idx = t * 8 + i;
    v[i] = (idx < lim) ? p[idx] : 0; s += v[i];
  }
  int x = s;
  #pragma unroll
  for (int d = 1; d < 64; d <<= 1){ int y = __shfl_up(x, d); if (l >= d) x += y; }
  if (l == 63) wt[wid] = x;
  __syncthreads();
  int wexc = 0;
  #pragma unroll
  for (int k = 0; k < 4; ++k) if (k < wid) wexc += wt[k];
  int te = s_bexc + wexc + (x - s);
  #pragma unroll
  for (int i = 0; i < 8; ++i){
    int idx = t * 8 + i;
    if (idx < lim) off[idx] = te;
    te += v[i];
  }
  if (c == NCH - 1 && t == 0)
    offsets[e * (NN + 1) + NN] = s_bexc + wt[0] + wt[1] + wt[2] + wt[3];
}

// fill + degval accumulation (fused: saves a separate pass over eval)
__global__ void k_fill(const int* __restrict__ erow, const int* __restrict__ ecol,
                       const float* __restrict__ eval, const int* __restrict__ offsets,
                       int* __restrict__ cursor, uint2* __restrict__ sedge,
                       float* __restrict__ degval){
  int idx = blockIdx.x * 256 + threadIdx.x;
  if (idx >= ETT * EE) return;
  int e = idx / EE;
  int row = erow[idx];
  float v = eval[idx];
  int pos = atomicAdd(&cursor[e * NN + row], 1);
  int o = offsets[e * (NN + 1) + row] + pos;
  sedge[e * EE + o] = make_uint2((uint32_t)ecol[idx], __builtin_bit_cast(uint32_t, v));
  atomicAdd(&degval[e * NN + row], v);
}

// ---------------------------------------------------------------- merged converts
// h0 = fp16(x); wcatT[t][f][e*128+d] = weight[t][e][d][f]; wgru fragment-major;
// bcomb = bih+bhh (r,z parts)
__global__ void k_conv(const float* __restrict__ x, const float* __restrict__ weight,
                       const float* __restrict__ wih, const float* __restrict__ whh,
                       const float* __restrict__ bih, const float* __restrict__ bhh,
                       uint16_t* __restrict__ hh, uint16_t* __restrict__ wcatT,
                       uint16_t* __restrict__ wgru, float* __restrict__ bcomb){
  int idx = blockIdx.x * 256 + threadIdx.x;
  if (idx < NN * DD / 8){
    const float4* xp = (const float4*)x;
    float4 a = xp[idx * 2], b = xp[idx * 2 + 1];
    uint32_t p0 = f2h(a.x) | (f2h(a.y) << 16);
    uint32_t p1 = f2h(a.z) | (f2h(a.w) << 16);
    uint32_t p2 = f2h(b.x) | (f2h(b.y) << 16);
    uint32_t p3 = f2h(b.z) | (f2h(b.w) << 16);
    ((uint4*)hh)[idx] = make_uint4(p0, p1, p2, p3);
  }
  if (idx < TT * 128 * 512){
    int t = idx / 65536; int rem = idx - t * 65536;
    int f = rem >> 9; int u = rem & 511;
    int e = u >> 7; int d = u & 127;
    wcatT[idx] = (uint16_t)f2bf(weight[(((t * 4 + e) * 128 + d) << 7) + f]);
  }
  if (idx < 192 * 512){                           // 98304 wgru elems
    const int frag = idx >> 9, within = idx & 511;
    const int lane = within >> 3, i = within & 7;
    const int ks = frag & 3, bb = (frag >> 2) & 1, m = (frag >> 3) & 1;
    const int rem2 = frag >> 4;                   // 0..11
    const int g = rem2 % 3, w = rem2 / 3;
    const int j = g * 128 + w * 32 + bb * 16 + (lane & 15);
    const int k = ks * 32 + (lane >> 4) * 8 + i;
    const float* src = m ? whh : wih;
    wgru[idx] = (uint16_t)f2bf(src[j * 128 + k]);
  }
  if (idx < 256) bcomb[idx] = bih[idx] + bhh[idx];
}

// ------------------------------------------------- fused gather + GEMM1 + GRU
// R15 champion structure; h-writes on non-last steps staged through shB for
// full-line coalesced stores.
#define HACC8(val, u, base) \
  fmamix_lo(acc[base+0], u.x, val); fmamix_hi(acc[base+1], u.x, val); \
  fmamix_lo(acc[base+2], u.y, val); fmamix_hi(acc[base+3], u.y, val); \
  fmamix_lo(acc[base+4], u.z, val); fmamix_hi(acc[base+5], u.z, val); \
  fmamix_lo(acc[base+6], u.w, val); fmamix_hi(acc[base+7], u.w, val);

__global__ __launch_bounds__(256, 4) void k_step(
    const uint16_t* __restrict__ hsrc, uint16_t* __restrict__ hdst,
    float* __restrict__ out_f32, int last,
    const int* __restrict__ offsets, const uint2* __restrict__ sedge,
    const float* __restrict__ degval, const float* __restrict__ bias_w,
    const uint16_t* __restrict__ wcatT_t, int tstep,
    const uint16_t* __restrict__ wgru, const float* __restrict__ bcomb,
    const float* __restrict__ b_ih, const float* __restrict__ b_hh)
{
  __shared__ uint16_t aggT[32 * 512];             // 32 KiB; front 8 KiB reused as mT
  __shared__ uint4 shB[512];                      // 8 KiB: hT, then output staging
  const int tid = threadIdx.x;
  const int node0 = blockIdx.x * 32;              // 3125 blocks exact

  { // ---- Phase 1: gather (8 thr/node x 16 dims, 6-way edge batching) ----
    const int nl = tid >> 3, q = tid & 7;
    const int n = node0 + nl;
    #pragma unroll
    for (int e = 0; e < ETT; ++e){
      float acc[16];
      #pragma unroll
      for (int i = 0; i < 16; ++i) acc[i] = 0.f;
      const int s  = offsets[e * (NN + 1) + n];
      const int en = offsets[e * (NN + 1) + n + 1];
      const uint2* ep = sedge + (size_t)e * EE;
      #pragma unroll 1
      for (int i = s; i < en; i += 6){
        const int lastI = en - 1;
        uint2 cv[6]; float vv[6];
        #pragma unroll
        for (int j = 0; j < 6; ++j){
          const int k = i + j;
          const int kc = (k < lastI) ? k : lastI;
          cv[j] = ep[kc];
          vv[j] = (k <= lastI) ? __builtin_bit_cast(float, cv[j].y) : 0.f;
        }
        uint4 ua[6], ub[6];
        #pragma unroll
        for (int j = 0; j < 6; ++j){
          const uint4* p = (const uint4*)(hsrc + (size_t)cv[j].x * DD + q * 16);
          ua[j] = p[0]; ub[j] = p[1];
        }
        #pragma unroll
        for (int j = 0; j < 6; ++j){
          const float v = vv[j];
          HACC8(v, ua[j], 0); HACC8(v, ub[j], 8);
        }
      }
      #pragma unroll
      for (int c2 = 0; c2 < 2; ++c2){
        const int c  = e * 16 + q * 2 + c2;       // logical 16B chunk (0..63)
        const int cs = c ^ (nl & 7);
        uint32_t p0 = f2bf(acc[c2*8+0]) | (f2bf(acc[c2*8+1]) << 16);
        uint32_t p1 = f2bf(acc[c2*8+2]) | (f2bf(acc[c2*8+3]) << 16);
        uint32_t p2 = f2bf(acc[c2*8+4]) | (f2bf(acc[c2*8+5]) << 16);
        uint32_t p3 = f2bf(acc[c2*8+6]) | (f2bf(acc[c2*8+7]) << 16);
        *(uint4*)&aggT[nl * 512 + cs * 8] = make_uint4(p0, p1, p2, p3);
      }
    }
  }
  __syncthreads();

  const int lane = tid & 63, w = tid >> 6;
  const int rlo = lane & 15, kg = lane >> 4;

  // ---- stage hT into shB: fp16 rows -> bf16 fragments (overlaps GEMM) ----
  #pragma unroll
  for (int i = 0; i < 2; ++i){
    const int slot = tid * 2 + i;                 // sn*16 + scs
    const int sn = slot >> 4, scs = slot & 15;
    const int sc = scs ^ (sn & 7);
    const uint4 hr = *(const uint4*)(hsrc + (size_t)(node0 + sn) * DD + sc * 8);
    uint32_t r0 = f2bf(h2f(hr.x & 0xffffu)) | (f2bf(h2f(hr.x >> 16)) << 16);
    uint32_t r1 = f2bf(h2f(hr.y & 0xffffu)) | (f2bf(h2f(hr.y >> 16)) << 16);
    uint32_t r2 = f2bf(h2f(hr.z & 0xffffu)) | (f2bf(h2f(hr.z >> 16)) << 16);
    uint32_t r3 = f2bf(h2f(hr.w & 0xffffu)) | (f2bf(h2f(hr.w >> 16)) << 16);
    shB[slot] = make_uint4(r0, r1, r2, r3);
  }

  // ---- Phase 2: GEMM C[32x128] = aggT[32x512] * Wcat[512x128] ----
  const int rt = w & 1, fh = w >> 1;
  const int rowA = rt * 16 + rlo;
  f32x4 C[4];
  #pragma unroll
  for (int i = 0; i < 4; ++i) C[i] = f32x4{0.f, 0.f, 0.f, 0.f};

  #pragma unroll
  for (int ks = 0; ks < 16; ++ks){
    const int cs = (ks * 4 + kg) ^ (rowA & 7);
    bf16x8 a = __builtin_bit_cast(bf16x8, *(const uint4*)&aggT[rowA * 512 + cs * 8]);
    #pragma unroll
    for (int ft = 0; ft < 4; ++ft){
      const int f = fh * 64 + ft * 16 + rlo;
      bf16x8 b = __builtin_bit_cast(bf16x8, *(const uint4*)(wcatT_t + (size_t)f * 512 + ks * 32 + kg * 8));
      C[ft] = mfma16(a, b, C[ft]);
    }
  }

  const float* bwt = bias_w + tstep * (ETT * DD);
  float dv[4][4];
  #pragma unroll
  for (int r = 0; r < 4; ++r){
    const int n2 = node0 + rt * 16 + kg * 4 + r;
    #pragma unroll
    for (int e = 0; e < 4; ++e) dv[e][r] = degval[e * NN + n2];
  }
  __syncthreads();                                // all aggT reads done before mT overwrite

  // ---- Phase 3: m_sum -> mT (swizzled u16 scatter into aggT front 8KB) ----
  uint16_t* mT = aggT;
  #pragma unroll
  for (int ft = 0; ft < 4; ++ft){
    const int f = fh * 64 + ft * 16 + rlo;
    const float b0 = bwt[f], b1 = bwt[128 + f], b2 = bwt[256 + f], b3 = bwt[384 + f];
    #pragma unroll
    for (int r = 0; r < 4; ++r){
      const int n2l = rt * 16 + kg * 4 + r;
      const float bias = dv[0][r]*b0 + dv[1][r]*b1 + dv[2][r]*b2 + dv[3][r]*b3;
      mT[n2l * 128 + (((f >> 3) ^ (n2l & 7)) << 3) + (f & 7)] = (uint16_t)f2bf(C[ft][r] + bias);
    }
  }
  __syncthreads();

  // ---- Phase 4: GRU (wave w owns dims [w*32, w*32+32), two bb-passes) ----
  const uint4* mT4 = (const uint4*)aggT;
  uint2 qv[2][2];                                 // [bb][ns] fp16 outputs (static idx)
  #pragma unroll
  for (int bb = 0; bb < 2; ++bb){
    f32x4 acc[3][2][2];                           // [gate][mat][ns]
    #pragma unroll
    for (int g = 0; g < 3; ++g)
      #pragma unroll
      for (int m = 0; m < 2; ++m)
        #pragma unroll
        for (int ns = 0; ns < 2; ++ns) acc[g][m][ns] = f32x4{0.f,0.f,0.f,0.f};

    #pragma unroll
    for (int ks = 0; ks < 4; ++ks){
      bf16x8 fa[3], fb[3];
      #pragma unroll
      for (int g = 0; g < 3; ++g){
        const int fragA = (((w * 3 + g) * 2 + 0) * 2 + bb) * 4 + ks;
        const int fragB = (((w * 3 + g) * 2 + 1) * 2 + bb) * 4 + ks;
        fa[g] = __builtin_bit_cast(bf16x8, *(const uint4*)(wgru + fragA * 512 + lane * 8));
        fb[g] = __builtin_bit_cast(bf16x8, *(const uint4*)(wgru + fragB * 512 + lane * 8));
      }
      #pragma unroll
      for (int ns = 0; ns < 2; ++ns){
        const int node = ns * 16 + rlo;
        const int cs = (ks * 4 + kg) ^ (node & 7);
        const bf16x8 bm = __builtin_bit_cast(bf16x8, mT4[node * 16 + cs]);
        const bf16x8 bh = __builtin_bit_cast(bf16x8, shB[node * 16 + cs]);
        #pragma unroll
        for (int g = 0; g < 3; ++g){
          acc[g][0][ns] = mfma16(fa[g], bm, acc[g][0][ns]);
          acc[g][1][ns] = mfma16(fb[g], bh, acc[g][1][ns]);
        }
      }
    }

    const int d0 = w * 32 + bb * 16 + kg * 4;
    const f32x4 brz = *(const f32x4*)(bcomb + d0);
    const f32x4 bzz = *(const f32x4*)(bcomb + 128 + d0);
    const f32x4 bin = *(const f32x4*)(b_ih + 256 + d0);
    const f32x4 bhn = *(const f32x4*)(b_hh + 256 + d0);
    #pragma unroll
    for (int ns = 0; ns < 2; ++ns){
      const int node = node0 + ns * 16 + rlo;
      const uint2 hov = *(const uint2*)(hsrc + (size_t)node * DD + d0);  // fp16 h_old, L2-hot
      const float ho[4] = { h2f(hov.x & 0xffffu), h2f(hov.x >> 16),
                            h2f(hov.y & 0xffffu), h2f(hov.y >> 16) };
      float hv[4];
      #pragma unroll
      for (int r = 0; r < 4; ++r){
        const float rg = 1.f / (1.f + __expf(-(acc[0][0][ns][r] + acc[0][1][ns][r] + brz[r])));
        const float zg = 1.f / (1.f + __expf(-(acc[1][0][ns][r] + acc[1][1][ns][r] + bzz[r])));
        const float xa = (acc[2][0][ns][r] + bin[r]) + rg * (acc[2][1][ns][r] + bhn[r]);
        const float ng = 1.f - 2.f / (__expf(2.f * xa) + 1.f);   // tanh
        hv[r] = (1.f - zg) * ng + zg * ho[r];
      }
      if (last){
        *(f32x4*)(out_f32 + (size_t)node * DD + d0) = f32x4{hv[0], hv[1], hv[2], hv[3]};
      } else {
        qv[bb][ns] = make_uint2(f2h(hv[0]) | (f2h(hv[1]) << 16),
                                f2h(hv[2]) | (f2h(hv[3]) << 16));
      }
    }
  }

  // ---- coalesced fp16 h-write via shB staging (non-last steps) ----
  if (!last){
    __syncthreads();                              // all shB (hT) reads done
    uint16_t* oT = (uint16_t*)shB;
    #pragma unroll
    for (int bb = 0; bb < 2; ++bb){
      #pragma unroll
      for (int ns = 0; ns < 2; ++ns){
        const int node = ns * 16 + rlo;           // local node 0..31
        const int cw  = w * 4 + bb * 2 + (kg >> 1);      // 16B chunk 0..15
        const int cws = cw ^ (node & 7);
        *(uint2*)((char*)oT + node * 256 + cws * 16 + (kg & 1) * 8) = qv[bb][ns];
      }
    }
    __syncthreads();
    #pragma unroll
    for (int i = 0; i < 2; ++i){
      const int slot = tid * 2 + i;               // node*16 + p
      const int sn = slot >> 4, p = slot & 15;
      const uint4 val = *(const uint4*)((char*)oT + sn * 256 + (p ^ (sn & 7)) * 16);
      *(uint4*)(hdst + (size_t)(node0 + sn) * DD + p * 8) = val;
    }
  }
}

// ---------------------------------------------------------------- launch
extern "C" void kernel_launch(void* const* d_in, const int* in_sizes, int n_in,
                              void* d_out, int out_size, void* d_ws, size_t ws_size,
                              hipStream_t stream) {
  const float* x      = (const float*)d_in[0];
  const int*   erow   = (const int*)d_in[1];
  const int*   ecol   = (const int*)d_in[2];
  const float* eval   = (const float*)d_in[3];
  const float* weight = (const float*)d_in[4];
  const float* bias_w = (const float*)d_in[5];
  const float* wih    = (const float*)d_in[6];
  const float* whh    = (const float*)d_in[7];
  const float* bih    = (const float*)d_in[8];
  const float* bhh    = (const float*)d_in[9];
  float* out = (float*)d_out;
  char* ws = (char*)d_ws;

  size_t o = 0;
  auto alloc = [&](size_t bytes)->char*{ char* p = ws + o; o += (bytes + 255) & ~(size_t)255; return p; };
  int*      counts  = (int*)     alloc((size_t)ETT * NN * 4);        // zeroed
  int*      cursor  = (int*)     alloc((size_t)ETT * NN * 4);        // zeroed
  float*    degval  = (float*)   alloc((size_t)ETT * NN * 4);        // zeroed
  int*      offsets = (int*)     alloc((size_t)ETT * (NN + 1) * 4);
  int*      bsum    = (int*)     alloc((size_t)ETT * NCH * 4);
  uint2*    sedge   = (uint2*)   alloc((size_t)ETT * EE * 8);
  uint16_t* hh0     = (uint16_t*)alloc((size_t)NN * DD * 2);         // fp16 h ping
  uint16_t* hh1     = (uint16_t*)alloc((size_t)NN * DD * 2);         // fp16 h pong
  uint16_t* wcatT   = (uint16_t*)alloc((size_t)TT * 128 * 512 * 2);
  uint16_t* wgru    = (uint16_t*)alloc((size_t)192 * 512 * 2);
  float*    bcomb   = (float*)   alloc((size_t)256 * 4);
  (void)ws_size; (void)in_sizes; (void)n_in; (void)out_size;

  // counts/cursor/degval contiguous (each 1.6MB, 256-aligned exactly)
  hipMemsetAsync(counts, 0, (size_t)3 * ETT * NN * 4, stream);

  k_count<<<(ETT * EE + 255) / 256, 256, 0, stream>>>(erow, counts);
  k_blksum<<<ETT * NCH, 256, 0, stream>>>(counts, bsum);
  k_apply<<<ETT * NCH, 256, 0, stream>>>(counts, bsum, offsets);
  k_fill<<<(ETT * EE + 255) / 256, 256, 0, stream>>>(erow, ecol, eval, offsets,
                                                     cursor, sedge, degval);
  k_conv<<<(NN * DD / 8 + 255) / 256, 256, 0, stream>>>(x, weight, wih, whh, bih, bhh,
                                                        hh0, wcatT, wgru, bcomb);

  uint16_t* hs = hh0;
  uint16_t* hd = hh1;
  for (int t = 0; t < TT; ++t){
    const int last = (t == TT - 1);
    k_step<<<NN / 32, 256, 0, stream>>>(hs, hd, out, last, offsets, sedge, degval,
                                        bias_w, wcatT + (size_t)t * 65536, t,
                                        wgru, bcomb, bih, bhh);
    uint16_t* tmp = hs; hs = hd; hd = tmp;
  }
}

// Round 17
// 665.413 us; speedup vs baseline: 1.0261x; 1.0261x over previous
//
#include <hip/hip_runtime.h>
#include <hip/hip_fp16.h>
#include <stdint.h>

// Problem constants (GatedGraphConv_26585847562966)
#define NN  100000   // nodes
#define DD  128      // feature dim
#define TT  3        // timesteps
#define ETT 4        // edge types
#define EE  250000   // edges per type
#define NCH 49       // scan chunks per etype (2048 elems each)

typedef float  f32x4  __attribute__((ext_vector_type(4)));
typedef __bf16 bf16x8 __attribute__((ext_vector_type(8)));

__device__ __forceinline__ float bf2f(uint32_t u){ u <<= 16; return __builtin_bit_cast(float, u); }
__device__ __forceinline__ uint32_t f2bf(float f){
  uint32_t u = __builtin_bit_cast(uint32_t, f);
  return (u + 0x7FFFu + ((u >> 16) & 1u)) >> 16;   // RNE, low 16 bits valid
}
__device__ __forceinline__ float h2f(uint32_t u){ return __half2float(__ushort_as_half((uint16_t)u)); }
__device__ __forceinline__ uint32_t f2h(float f){ return (uint32_t)__half_as_ushort(__float2half(f)); }
__device__ __forceinline__ f32x4 mfma16(bf16x8 a, bf16x8 b, f32x4 c){
  return __builtin_amdgcn_mfma_f32_16x16x32_bf16(a, b, c, 0, 0, 0);
}
// acc = fp16(lo/hi half of h) * v + acc, single VOP3P instruction
__device__ __forceinline__ void fmamix_lo(float& acc, uint32_t h, float v){
  asm("v_fma_mix_f32 %0, %1, %2, %0 op_sel:[0,0,0] op_sel_hi:[1,0,0]"
      : "+v"(acc) : "v"(h), "v"(v));
}
__device__ __forceinline__ void fmamix_hi(float& acc, uint32_t h, float v){
  asm("v_fma_mix_f32 %0, %1, %2, %0 op_sel:[1,0,0] op_sel_hi:[1,0,0]"
      : "+v"(acc) : "v"(h), "v"(v));
}

// ---------------------------------------------------------------- CSR build (per etype)
__global__ void k_count(const int* __restrict__ erow, int* __restrict__ counts){
  int idx = blockIdx.x * 256 + threadIdx.x;
  if (idx >= ETT * EE) return;
  int e = idx / EE;
  atomicAdd(&counts[e * NN + erow[idx]], 1);
}

__global__ void k_blksum(const int* __restrict__ counts, int* __restrict__ bsum){
  const int b = blockIdx.x, e = b / NCH, c = b % NCH;
  const int* p = counts + e * NN + c * 2048;
  int lim = NN - c * 2048; if (lim > 2048) lim = 2048;
  const int t = threadIdx.x;
  int s = 0;
  #pragma unroll
  for (int i = 0; i < 8; ++i){
    int idx = i * 256 + t;
    if (idx < lim) s += p[idx];
  }
  #pragma unroll
  for (int d = 32; d; d >>= 1) s += __shfl_down(s, d);
  __shared__ int wsum[4];
  if ((t & 63) == 0) wsum[t >> 6] = s;
  __syncthreads();
  if (t == 0) bsum[b] = wsum[0] + wsum[1] + wsum[2] + wsum[3];
}

// per-chunk exclusive scan; block-local re-reduction of bsum gives the chunk base
__global__ void k_apply(const int* __restrict__ counts, const int* __restrict__ bsum,
                        int* __restrict__ offsets){
  const int b = blockIdx.x, e = b / NCH, c = b % NCH;
  const int* p = counts + e * NN + c * 2048;
  int* off = offsets + e * (NN + 1) + c * 2048;
  int lim = NN - c * 2048; if (lim > 2048) lim = 2048;
  const int t = threadIdx.x, l = t & 63, wid = t >> 6;
  __shared__ int wt[4];
  __shared__ int s_bexc;
  if (wid == 0){                                  // chunk base = sum of prior chunk sums
    int vb = (l < c) ? bsum[e * NCH + l] : 0;
    #pragma unroll
    for (int d = 32; d; d >>= 1) vb += __shfl_down(vb, d);
    if (l == 0) s_bexc = vb;
  }
  int v[8], s = 0;
  #pragma unroll
  for (int i = 0; i < 8; ++i){
    int idx = t * 8 + i;
    v[i] = (idx < lim) ? p[idx] : 0; s += v[i];
  }
  int x = s;
  #pragma unroll
  for (int d = 1; d < 64; d <<= 1){ int y = __shfl_up(x, d); if (l >= d) x += y; }
  if (l == 63) wt[wid] = x;
  __syncthreads();
  int wexc = 0;
  #pragma unroll
  for (int k = 0; k < 4; ++k) if (k < wid) wexc += wt[k];
  int te = s_bexc + wexc + (x - s);
  #pragma unroll
  for (int i = 0; i < 8; ++i){
    int idx = t * 8 + i;
    if (idx < lim) off[idx] = te;
    te += v[i];
  }
  if (c == NCH - 1 && t == 0)
    offsets[e * (NN + 1) + NN] = s_bexc + wt[0] + wt[1] + wt[2] + wt[3];
}

// fill + degval accumulation (fused: saves a separate pass over eval)
__global__ void k_fill(const int* __restrict__ erow, const int* __restrict__ ecol,
                       const float* __restrict__ eval, const int* __restrict__ offsets,
                       int* __restrict__ cursor, uint2* __restrict__ sedge,
                       float* __restrict__ degval){
  int idx = blockIdx.x * 256 + threadIdx.x;
  if (idx >= ETT * EE) return;
  int e = idx / EE;
  int row = erow[idx];
  float v = eval[idx];
  int pos = atomicAdd(&cursor[e * NN + row], 1);
  int o = offsets[e * (NN + 1) + row] + pos;
  sedge[e * EE + o] = make_uint2((uint32_t)ecol[idx], __builtin_bit_cast(uint32_t, v));
  atomicAdd(&degval[e * NN + row], v);
}

// ---------------------------------------------------------------- merged converts
// h0 = fp16(x); wcatT[t][f][e*128+d] = weight[t][e][d][f]; wgru fragment-major;
// bcomb = bih+bhh (r,z parts)
__global__ void k_conv(const float* __restrict__ x, const float* __restrict__ weight,
                       const float* __restrict__ wih, const float* __restrict__ whh,
                       const float* __restrict__ bih, const float* __restrict__ bhh,
                       uint16_t* __restrict__ hh, uint16_t* __restrict__ wcatT,
                       uint16_t* __restrict__ wgru, float* __restrict__ bcomb){
  int idx = blockIdx.x * 256 + threadIdx.x;
  if (idx < NN * DD / 8){
    const float4* xp = (const float4*)x;
    float4 a = xp[idx * 2], b = xp[idx * 2 + 1];
    uint32_t p0 = f2h(a.x) | (f2h(a.y) << 16);
    uint32_t p1 = f2h(a.z) | (f2h(a.w) << 16);
    uint32_t p2 = f2h(b.x) | (f2h(b.y) << 16);
    uint32_t p3 = f2h(b.z) | (f2h(b.w) << 16);
    ((uint4*)hh)[idx] = make_uint4(p0, p1, p2, p3);
  }
  if (idx < TT * 128 * 512){
    int t = idx / 65536; int rem = idx - t * 65536;
    int f = rem >> 9; int u = rem & 511;
    int e = u >> 7; int d = u & 127;
    wcatT[idx] = (uint16_t)f2bf(weight[(((t * 4 + e) * 128 + d) << 7) + f]);
  }
  if (idx < 192 * 512){                           // 98304 wgru elems
    const int frag = idx >> 9, within = idx & 511;
    const int lane = within >> 3, i = within & 7;
    const int ks = frag & 3, bb = (frag >> 2) & 1, m = (frag >> 3) & 1;
    const int rem2 = frag >> 4;                   // 0..11
    const int g = rem2 % 3, w = rem2 / 3;
    const int j = g * 128 + w * 32 + bb * 16 + (lane & 15);
    const int k = ks * 32 + (lane >> 4) * 8 + i;
    const float* src = m ? whh : wih;
    wgru[idx] = (uint16_t)f2bf(src[j * 128 + k]);
  }
  if (idx < 256) bcomb[idx] = bih[idx] + bhh[idx];
}

// ------------------------------------------------- fused gather + GEMM1 + GRU
// R15 champion k_step: 6-way fmamix gather, 40KB LDS, direct h-writes.
#define HACC8(val, u, base) \
  fmamix_lo(acc[base+0], u.x, val); fmamix_hi(acc[base+1], u.x, val); \
  fmamix_lo(acc[base+2], u.y, val); fmamix_hi(acc[base+3], u.y, val); \
  fmamix_lo(acc[base+4], u.z, val); fmamix_hi(acc[base+5], u.z, val); \
  fmamix_lo(acc[base+6], u.w, val); fmamix_hi(acc[base+7], u.w, val);

__global__ __launch_bounds__(256, 4) void k_step(
    const uint16_t* __restrict__ hsrc, uint16_t* __restrict__ hdst,
    float* __restrict__ out_f32, int last,
    const int* __restrict__ offsets, const uint2* __restrict__ sedge,
    const float* __restrict__ degval, const float* __restrict__ bias_w,
    const uint16_t* __restrict__ wcatT_t, int tstep,
    const uint16_t* __restrict__ wgru, const float* __restrict__ bcomb,
    const float* __restrict__ b_ih, const float* __restrict__ b_hh)
{
  __shared__ uint16_t aggT[32 * 512];             // 32 KiB; front 8 KiB reused as mT
  __shared__ uint4 shB[512];                      // 8 KiB hT (bf16, swizzled)
  const int tid = threadIdx.x;
  const int node0 = blockIdx.x * 32;              // 3125 blocks exact

  { // ---- Phase 1: gather (8 thr/node x 16 dims, 6-way edge batching) ----
    const int nl = tid >> 3, q = tid & 7;
    const int n = node0 + nl;
    #pragma unroll
    for (int e = 0; e < ETT; ++e){
      float acc[16];
      #pragma unroll
      for (int i = 0; i < 16; ++i) acc[i] = 0.f;
      const int s  = offsets[e * (NN + 1) + n];
      const int en = offsets[e * (NN + 1) + n + 1];
      const uint2* ep = sedge + (size_t)e * EE;
      #pragma unroll 1
      for (int i = s; i < en; i += 6){
        const int lastI = en - 1;
        uint2 cv[6]; float vv[6];
        #pragma unroll
        for (int j = 0; j < 6; ++j){
          const int k = i + j;
          const int kc = (k < lastI) ? k : lastI;
          cv[j] = ep[kc];
          vv[j] = (k <= lastI) ? __builtin_bit_cast(float, cv[j].y) : 0.f;
        }
        uint4 ua[6], ub[6];
        #pragma unroll
        for (int j = 0; j < 6; ++j){
          const uint4* p = (const uint4*)(hsrc + (size_t)cv[j].x * DD + q * 16);
          ua[j] = p[0]; ub[j] = p[1];
        }
        #pragma unroll
        for (int j = 0; j < 6; ++j){
          const float v = vv[j];
          HACC8(v, ua[j], 0); HACC8(v, ub[j], 8);
        }
      }
      #pragma unroll
      for (int c2 = 0; c2 < 2; ++c2){
        const int c  = e * 16 + q * 2 + c2;       // logical 16B chunk (0..63)
        const int cs = c ^ (nl & 7);
        uint32_t p0 = f2bf(acc[c2*8+0]) | (f2bf(acc[c2*8+1]) << 16);
        uint32_t p1 = f2bf(acc[c2*8+2]) | (f2bf(acc[c2*8+3]) << 16);
        uint32_t p2 = f2bf(acc[c2*8+4]) | (f2bf(acc[c2*8+5]) << 16);
        uint32_t p3 = f2bf(acc[c2*8+6]) | (f2bf(acc[c2*8+7]) << 16);
        *(uint4*)&aggT[nl * 512 + cs * 8] = make_uint4(p0, p1, p2, p3);
      }
    }
  }
  __syncthreads();

  const int lane = tid & 63, w = tid >> 6;
  const int rlo = lane & 15, kg = lane >> 4;

  // ---- stage hT into shB: fp16 rows -> bf16 fragments (overlaps GEMM) ----
  #pragma unroll
  for (int i = 0; i < 2; ++i){
    const int slot = tid * 2 + i;                 // sn*16 + scs
    const int sn = slot >> 4, scs = slot & 15;
    const int sc = scs ^ (sn & 7);
    const uint4 hr = *(const uint4*)(hsrc + (size_t)(node0 + sn) * DD + sc * 8);
    uint32_t r0 = f2bf(h2f(hr.x & 0xffffu)) | (f2bf(h2f(hr.x >> 16)) << 16);
    uint32_t r1 = f2bf(h2f(hr.y & 0xffffu)) | (f2bf(h2f(hr.y >> 16)) << 16);
    uint32_t r2 = f2bf(h2f(hr.z & 0xffffu)) | (f2bf(h2f(hr.z >> 16)) << 16);
    uint32_t r3 = f2bf(h2f(hr.w & 0xffffu)) | (f2bf(h2f(hr.w >> 16)) << 16);
    shB[slot] = make_uint4(r0, r1, r2, r3);
  }

  // ---- Phase 2: GEMM C[32x128] = aggT[32x512] * Wcat[512x128] ----
  const int rt = w & 1, fh = w >> 1;
  const int rowA = rt * 16 + rlo;
  f32x4 C[4];
  #pragma unroll
  for (int i = 0; i < 4; ++i) C[i] = f32x4{0.f, 0.f, 0.f, 0.f};

  #pragma unroll
  for (int ks = 0; ks < 16; ++ks){
    const int cs = (ks * 4 + kg) ^ (rowA & 7);
    bf16x8 a = __builtin_bit_cast(bf16x8, *(const uint4*)&aggT[rowA * 512 + cs * 8]);
    #pragma unroll
    for (int ft = 0; ft < 4; ++ft){
      const int f = fh * 64 + ft * 16 + rlo;
      bf16x8 b = __builtin_bit_cast(bf16x8, *(const uint4*)(wcatT_t + (size_t)f * 512 + ks * 32 + kg * 8));
      C[ft] = mfma16(a, b, C[ft]);
    }
  }

  const float* bwt = bias_w + tstep * (ETT * DD);
  float dv[4][4];
  #pragma unroll
  for (int r = 0; r < 4; ++r){
    const int n2 = node0 + rt * 16 + kg * 4 + r;
    #pragma unroll
    for (int e = 0; e < 4; ++e) dv[e][r] = degval[e * NN + n2];
  }
  __syncthreads();                                // all aggT reads done before mT overwrite

  // ---- Phase 3: m_sum -> mT (swizzled u16 scatter into aggT front 8KB) ----
  uint16_t* mT = aggT;
  #pragma unroll
  for (int ft = 0; ft < 4; ++ft){
    const int f = fh * 64 + ft * 16 + rlo;
    const float b0 = bwt[f], b1 = bwt[128 + f], b2 = bwt[256 + f], b3 = bwt[384 + f];
    #pragma unroll
    for (int r = 0; r < 4; ++r){
      const int n2l = rt * 16 + kg * 4 + r;
      const float bias = dv[0][r]*b0 + dv[1][r]*b1 + dv[2][r]*b2 + dv[3][r]*b3;
      mT[n2l * 128 + (((f >> 3) ^ (n2l & 7)) << 3) + (f & 7)] = (uint16_t)f2bf(C[ft][r] + bias);
    }
  }
  __syncthreads();

  // ---- Phase 4: GRU (wave w owns dims [w*32, w*32+32), two bb-passes) ----
  const uint4* mT4 = (const uint4*)aggT;
  #pragma unroll
  for (int bb = 0; bb < 2; ++bb){
    f32x4 acc[3][2][2];                           // [gate][mat][ns]
    #pragma unroll
    for (int g = 0; g < 3; ++g)
      #pragma unroll
      for (int m = 0; m < 2; ++m)
        #pragma unroll
        for (int ns = 0; ns < 2; ++ns) acc[g][m][ns] = f32x4{0.f,0.f,0.f,0.f};

    #pragma unroll
    for (int ks = 0; ks < 4; ++ks){
      bf16x8 fa[3], fb[3];
      #pragma unroll
      for (int g = 0; g < 3; ++g){
        const int fragA = (((w * 3 + g) * 2 + 0) * 2 + bb) * 4 + ks;
        const int fragB = (((w * 3 + g) * 2 + 1) * 2 + bb) * 4 + ks;
        fa[g] = __builtin_bit_cast(bf16x8, *(const uint4*)(wgru + fragA * 512 + lane * 8));
        fb[g] = __builtin_bit_cast(bf16x8, *(const uint4*)(wgru + fragB * 512 + lane * 8));
      }
      #pragma unroll
      for (int ns = 0; ns < 2; ++ns){
        const int node = ns * 16 + rlo;
        const int cs = (ks * 4 + kg) ^ (node & 7);
        const bf16x8 bm = __builtin_bit_cast(bf16x8, mT4[node * 16 + cs]);
        const bf16x8 bh = __builtin_bit_cast(bf16x8, shB[node * 16 + cs]);
        #pragma unroll
        for (int g = 0; g < 3; ++g){
          acc[g][0][ns] = mfma16(fa[g], bm, acc[g][0][ns]);
          acc[g][1][ns] = mfma16(fb[g], bh, acc[g][1][ns]);
        }
      }
    }

    const int d0 = w * 32 + bb * 16 + kg * 4;
    const f32x4 brz = *(const f32x4*)(bcomb + d0);
    const f32x4 bzz = *(const f32x4*)(bcomb + 128 + d0);
    const f32x4 bin = *(const f32x4*)(b_ih + 256 + d0);
    const f32x4 bhn = *(const f32x4*)(b_hh + 256 + d0);
    #pragma unroll
    for (int ns = 0; ns < 2; ++ns){
      const int node = node0 + ns * 16 + rlo;
      const uint2 hov = *(const uint2*)(hsrc + (size_t)node * DD + d0);  // fp16 h_old, L2-hot
      const float ho[4] = { h2f(hov.x & 0xffffu), h2f(hov.x >> 16),
                            h2f(hov.y & 0xffffu), h2f(hov.y >> 16) };
      float hv[4];
      #pragma unroll
      for (int r = 0; r < 4; ++r){
        const float rg = 1.f / (1.f + __expf(-(acc[0][0][ns][r] + acc[0][1][ns][r] + brz[r])));
        const float zg = 1.f / (1.f + __expf(-(acc[1][0][ns][r] + acc[1][1][ns][r] + bzz[r])));
        const float xa = (acc[2][0][ns][r] + bin[r]) + rg * (acc[2][1][ns][r] + bhn[r]);
        const float ng = 1.f - 2.f / (__expf(2.f * xa) + 1.f);   // tanh
        hv[r] = (1.f - zg) * ng + zg * ho[r];
      }
      if (last){
        *(f32x4*)(out_f32 + (size_t)node * DD + d0) = f32x4{hv[0], hv[1], hv[2], hv[3]};
      } else {
        uint32_t q0 = f2h(hv[0]) | (f2h(hv[1]) << 16);
        uint32_t q1 = f2h(hv[2]) | (f2h(hv[3]) << 16);
        *(uint2*)(hdst + (size_t)node * DD + d0) = make_uint2(q0, q1);
      }
    }
  }
}

// ---------------------------------------------------------------- launch
extern "C" void kernel_launch(void* const* d_in, const int* in_sizes, int n_in,
                              void* d_out, int out_size, void* d_ws, size_t ws_size,
                              hipStream_t stream) {
  const float* x      = (const float*)d_in[0];
  const int*   erow   = (const int*)d_in[1];
  const int*   ecol   = (const int*)d_in[2];
  const float* eval   = (const float*)d_in[3];
  const float* weight = (const float*)d_in[4];
  const float* bias_w = (const float*)d_in[5];
  const float* wih    = (const float*)d_in[6];
  const float* whh    = (const float*)d_in[7];
  const float* bih    = (const float*)d_in[8];
  const float* bhh    = (const float*)d_in[9];
  float* out = (float*)d_out;
  char* ws = (char*)d_ws;

  size_t o = 0;
  auto alloc = [&](size_t bytes)->char*{ char* p = ws + o; o += (bytes + 255) & ~(size_t)255; return p; };
  int*      counts  = (int*)     alloc((size_t)ETT * NN * 4);        // zeroed
  int*      cursor  = (int*)     alloc((size_t)ETT * NN * 4);        // zeroed
  float*    degval  = (float*)   alloc((size_t)ETT * NN * 4);        // zeroed
  int*      offsets = (int*)     alloc((size_t)ETT * (NN + 1) * 4);
  int*      bsum    = (int*)     alloc((size_t)ETT * NCH * 4);
  uint2*    sedge   = (uint2*)   alloc((size_t)ETT * EE * 8);
  uint16_t* hh0     = (uint16_t*)alloc((size_t)NN * DD * 2);         // fp16 h ping
  uint16_t* hh1     = (uint16_t*)alloc((size_t)NN * DD * 2);         // fp16 h pong
  uint16_t* wcatT   = (uint16_t*)alloc((size_t)TT * 128 * 512 * 2);
  uint16_t* wgru    = (uint16_t*)alloc((size_t)192 * 512 * 2);
  float*    bcomb   = (float*)   alloc((size_t)256 * 4);
  (void)ws_size; (void)in_sizes; (void)n_in; (void)out_size;

  // counts/cursor/degval contiguous (each 1.6MB, 256-aligned exactly)
  hipMemsetAsync(counts, 0, (size_t)3 * ETT * NN * 4, stream);

  k_count<<<(ETT * EE + 255) / 256, 256, 0, stream>>>(erow, counts);
  k_blksum<<<ETT * NCH, 256, 0, stream>>>(counts, bsum);
  k_apply<<<ETT * NCH, 256, 0, stream>>>(counts, bsum, offsets);
  k_fill<<<(ETT * EE + 255) / 256, 256, 0, stream>>>(erow, ecol, eval, offsets,
                                                     cursor, sedge, degval);
  k_conv<<<(NN * DD / 8 + 255) / 256, 256, 0, stream>>>(x, weight, wih, whh, bih, bhh,
                                                        hh0, wcatT, wgru, bcomb);

  uint16_t* hs = hh0;
  uint16_t* hd = hh1;
  for (int t = 0; t < TT; ++t){
    const int last = (t == TT - 1);
    k_step<<<NN / 32, 256, 0, stream>>>(hs, hd, out, last, offsets, sedge, degval,
                                        bias_w, wcatT + (size_t)t * 65536, t,
                                        wgru, bcomb, bih, bhh);
    uint16_t* tmp = hs; hs = hd; hd = tmp;
  }
}